// Round 9
// baseline (809.018 us; speedup 1.0000x reference)
//
#include <hip/hip_runtime.h>
#include <hip/hip_bf16.h>
#include <hip/hip_cooperative_groups.h>
#include <stdint.h>

namespace cg = cooperative_groups;

// Problem constants (fixed by the reference)
#define N_EDGES   800000
#define N_NODESC  50000
#define HID       128

#define PREP_BLOCKS 782      // cooperative grid: 782*64 = 50048 >= 50000 buckets
#define BPB         64       // buckets (col nodes) per block, one wave-width

typedef __attribute__((ext_vector_type(8))) short bf16x8;  // 8 bf16 = 4 VGPRs (MFMA A/B frag)
typedef __attribute__((ext_vector_type(4))) float f32x4;   // MFMA C/D frag
typedef __attribute__((ext_vector_type(4))) unsigned int u32x4;

__device__ __forceinline__ short f2bf(float f) {
    union { float f; uint32_t u; } v; v.f = f;
    uint32_t r = v.u + 0x7FFFu + ((v.u >> 16) & 1u);   // round-to-nearest-even
    return (short)(r >> 16);
}

// pack two f32 -> bf16x2 (RNE) via native v_cvt_pk_bf16_f32 on gfx950
__device__ __forceinline__ uint32_t packbf2(float lo, float hi) {
    float2 t; t.x = lo; t.y = hi;
    __hip_bfloat162 h = __float22bfloat162_rn(t);
    uint32_t u;
    __builtin_memcpy(&u, &h, 4);       // __hip_bfloat162 not trivially copyable -> memcpy pun
    return u;
}

// packed bf16x2 (a+b) then relu: native v_pk_add_bf16 (one RNE rounding) + sign-mask relu
__device__ __forceinline__ uint32_t addrelu2(uint32_t a, uint32_t b) {
    __hip_bfloat162 ha, hb;
    __builtin_memcpy(&ha, &a, 4);
    __builtin_memcpy(&hb, &b, 4);
    __hip_bfloat162 s = __hadd2(ha, hb);
    uint32_t x;
    __builtin_memcpy(&x, &s, 4);
    uint32_t neg = (x & 0x80008000u) >> 15;      // 1 at bit0/bit16 where half negative
    return x & ~(neg * 0xFFFFu);                 // zero negative halves
}
__device__ __forceinline__ bf16x8 addrelu8(u32x4 p, u32x4 q) {
    u32x4 r;
    #pragma unroll
    for (int j = 0; j < 4; ++j) r[j] = addrelu2(p[j], q[j]);
    bf16x8 out;
    __builtin_memcpy(&out, &r, 16);
    return out;
}

// ---------------- workspace layout ----------------
// PQ  : bf16 [50000][1024]  (cols 0..511 = emb@W1_top + b1 "P'", 512..1023 = emb@W1_bot "Q")
// W1s : bf16 frag-major, 4*64 frags x 64 lanes x 8   (B-frags of W1cat [128,1024])
// W2s : bf16 frag-major, 16*8 frags x 64 lanes x 8   (B-frags of W2 [512,128])
// cnt/cursor : int[50000] per-col histogram / scatter cursors (counting sort by col)
// btot : int[PREP_BLOCKS] per-block bucket totals for the two-level scan
// pk  : uint2[800000]  col-sorted edges, packed (col<<16|row, eid)
#define PQ_OFF    0UL
#define W1S_OFF   102400000UL                 // 50000*1024*2
#define W2S_OFF   (W1S_OFF + 262144UL)
#define CNT_OFF   (W2S_OFF + 131072UL)
#define CUR_OFF   (CNT_OFF + 200000UL)
#define BTOT_OFF  (CUR_OFF + 200000UL)
#define PK_OFF    (BTOT_OFF + 4096UL)
// total ws needed: PK_OFF + 6,400,000 = 109,335,296 bytes

// ============ kernel 0 (cooperative): swizzle + zero + hist + scan + scatter ============
// One launch replaces 5 graph nodes (memset, swizzle, hist, scan, scatter): the R8
// prep measured ~113 us vs ~40 us arithmetic -> suspected per-node serialization.
// 782 blocks x 256 threads, trivially co-resident; grid.sync() between phases.
__global__ __launch_bounds__(256) void prep_kernel(const float* __restrict__ W1,
                                                   const float* __restrict__ W2,
                                                   short* __restrict__ W1s,
                                                   short* __restrict__ W2s,
                                                   const int* __restrict__ ei,
                                                   int* __restrict__ cnt,
                                                   int* __restrict__ btot,
                                                   int* __restrict__ cursor,
                                                   uint2* __restrict__ pk) {
    cg::grid_group grid = cg::this_grid();
    __shared__ int red[256];
    int tid = threadIdx.x;
    int b = blockIdx.x;
    int gid = b * 256 + tid;
    const int GSTRIDE = PREP_BLOCKS * 256;     // 200192

    // ---- ph0a: weight convert + B-frag swizzle (gid < 24576) ----
    // B-frag for 16x16x32 bf16: lane l holds B[k=kc*32+(l>>4)*8+j][n=nt*16+(l&15)]
    {
        int lane = gid & 63;
        int kq = lane >> 4;
        int nn = lane & 15;
        if (gid < 16384) {          // W1cat: K=128, N=1024 -> kc 0..3, nt 0..63
            int frag = gid >> 6;
            int kc = frag >> 6;
            int nt = frag & 63;
            int n = nt * 16 + nn;
            int kbase = kc * 32 + kq * 8;
            bf16x8 v;
            #pragma unroll
            for (int j = 0; j < 8; ++j) {
                int k = kbase + j;
                float f = (n < 512) ? W1[k * 512 + n] : W1[(128 + k) * 512 + (n - 512)];
                v[j] = f2bf(f);
            }
            *(bf16x8*)(W1s + frag * 512 + lane * 8) = v;
        } else if (gid < 24576) {   // W2: K=512, N=128 -> kc 0..15, nt 0..7
            int t2 = gid - 16384;
            int frag = t2 >> 6;
            int kc = frag >> 3;
            int nt = frag & 7;
            int n = nt * 16 + nn;
            int kbase = kc * 32 + kq * 8;
            bf16x8 v;
            #pragma unroll
            for (int j = 0; j < 8; ++j) v[j] = f2bf(W2[(kbase + j) * HID + n]);
            *(bf16x8*)(W2s + frag * 512 + lane * 8) = v;
        }
    }
    // ---- ph0b: zero histogram ----
    if (gid < N_NODESC) cnt[gid] = 0;
    grid.sync();

    // ---- ph1: histogram of col ----
    for (int e = gid; e < N_EDGES; e += GSTRIDE)
        atomicAdd(&cnt[ei[e]], 1);
    grid.sync();

    // ---- ph2a: per-block bucket total (buckets [64b, 64b+64)) ----
    if (tid < 64) {
        int idx = b * BPB + tid;
        int v = (idx < N_NODESC) ? cnt[idx] : 0;
        #pragma unroll
        for (int off = 32; off; off >>= 1) v += __shfl_down(v, off, 64);
        if (tid == 0) btot[b] = v;
    }
    grid.sync();

    // ---- ph2b: exclusive block offset + in-block bucket prefix -> cursor ----
    int part = 0;
    for (int j = tid; j < b; j += 256) part += btot[j];
    red[tid] = part;
    __syncthreads();
    #pragma unroll
    for (int s = 128; s; s >>= 1) {
        if (tid < s) red[tid] += red[tid + s];
        __syncthreads();
    }
    if (tid < 64) {
        int idx = b * BPB + tid;
        int v = (idx < N_NODESC) ? cnt[idx] : 0;
        int run = v;
        #pragma unroll
        for (int off = 1; off < 64; off <<= 1) {
            int t = __shfl_up(run, off, 64);
            if (tid >= off) run += t;
        }
        if (idx < N_NODESC) cursor[idx] = red[0] + run - v;   // exclusive prefix
    }
    grid.sync();

    // ---- ph3: scatter packed (col<<16|row, eid), col-sorted ----
    for (int e = gid; e < N_EDGES; e += GSTRIDE) {
        int c = ei[e];
        int r = ei[N_EDGES + e];
        int slot = atomicAdd(&cursor[c], 1);
        uint2 v;
        v.x = ((uint32_t)c << 16) | (uint32_t)r;
        v.y = (uint32_t)e;
        pk[slot] = v;
    }
}

// ============ kernel 1: PQ = emb @ W1cat (+b1 on P half) — exact R6 version ============
// grid 3125 x 256: block = 16 node rows, 4 waves each owning a 256-col slice.
// C-tile -> per-wave LDS transpose -> coalesced dwordx4 stores (no barriers).
__global__ __launch_bounds__(256) void precompute_kernel(const float* __restrict__ emb,
                                                         const short* __restrict__ W1s,
                                                         const float* __restrict__ b1,
                                                         short* __restrict__ PQ) {
    __shared__ short tile[4][16][272];   // 16 rows x 256 cols, stride 272 shorts (544 B)
    int lane = threadIdx.x & 63;
    int w = threadIdx.x >> 6;
    int nb = blockIdx.x * 16;
    int m = lane & 15;
    int kq = lane >> 4;

    const float* arow = emb + (size_t)(nb + m) * 128 + kq * 8;

    f32x4 acc[16];
    #pragma unroll
    for (int i = 0; i < 16; ++i) acc[i] = (f32x4){0.f, 0.f, 0.f, 0.f};

    #pragma unroll
    for (int kc = 0; kc < 4; ++kc) {
        f32x4 x0 = *(const f32x4*)(arow + kc * 32);
        f32x4 x1 = *(const f32x4*)(arow + kc * 32 + 4);
        u32x4 au;
        au[0] = packbf2(x0[0], x0[1]); au[1] = packbf2(x0[2], x0[3]);
        au[2] = packbf2(x1[0], x1[1]); au[3] = packbf2(x1[2], x1[3]);
        bf16x8 a;
        __builtin_memcpy(&a, &au, 16);
        #pragma unroll
        for (int nt = 0; nt < 16; ++nt) {
            int frag = kc * 64 + (w * 16 + nt);
            bf16x8 bb = *(const bf16x8*)(W1s + frag * 512 + lane * 8);
            acc[nt] = __builtin_amdgcn_mfma_f32_16x16x32_bf16(a, bb, acc[nt], 0, 0, 0);
        }
    }

    // C/D layout: col = lane&15, row = (lane>>4)*4 + r.  Fold b1 into the P half (n<512).
    #pragma unroll
    for (int nt = 0; nt < 16; ++nt) {
        int n = w * 256 + nt * 16 + m;
        float bias = (n < 512) ? b1[n] : 0.0f;
        #pragma unroll
        for (int r = 0; r < 4; ++r)
            tile[w][kq * 4 + r][nt * 16 + m] = f2bf(acc[nt][r] + bias);
    }

    #pragma unroll
    for (int s = 0; s < 8; ++s) {
        int row = s * 2 + (lane >> 5);
        int chunk = lane & 31;
        bf16x8 v = *(const bf16x8*)(&tile[w][row][chunk * 8]);
        *(bf16x8*)(PQ + (size_t)(nb + row) * 1024 + w * 256 + chunk * 8) = v;
    }
}

// ============ kernel 2: per-edge fused MLP on col-sorted edges (R7 structure) ============
// grid 3125 x 256: each wave owns 64 sorted edges (4 m-tiles).  Col-sort -> ~4 distinct
// P rows per wave (L1-resident) + sequential P walk.  Output scattered via packed eid.
__global__ __launch_bounds__(256, 2) void edge_kernel(const short* __restrict__ PQ,
                                                      const uint2* __restrict__ pk,
                                                      const short* __restrict__ W2s,
                                                      const float* __restrict__ b2,
                                                      const float* __restrict__ W3,
                                                      const float* __restrict__ b3,
                                                      float* __restrict__ out) {
    int lane = threadIdx.x & 63;
    int w = threadIdx.x >> 6;
    int e0 = blockIdx.x * 256 + w * 64;
    int m = lane & 15;
    int kq = lane >> 4;

    uint2 pe = pk[e0 + lane];
    int idx_c = (int)(pe.x >> 16);
    int idx_r = (int)(pe.x & 0xFFFFu);
    int eid   = (int)pe.y;

    const short* pb[4];
    const short* qb[4];
    #pragma unroll
    for (int t = 0; t < 4; ++t) {
        int ce = __shfl(idx_c, t * 16 + m, 64);
        int re = __shfl(idx_r, t * 16 + m, 64);
        pb[t] = PQ + (size_t)ce * 1024 + kq * 8;          // P' half
        qb[t] = PQ + (size_t)re * 1024 + 512 + kq * 8;    // Q half
    }

    f32x4 acc[4][8];
    #pragma unroll
    for (int t = 0; t < 4; ++t)
        #pragma unroll
        for (int nt = 0; nt < 8; ++nt) acc[t][nt] = (f32x4){0.f, 0.f, 0.f, 0.f};

    #pragma unroll
    for (int kc = 0; kc < 16; ++kc) {
        u32x4 p[4], q[4];
        #pragma unroll
        for (int t = 0; t < 4; ++t) {
            p[t] = *(const u32x4*)(pb[t] + kc * 32);
            q[t] = *(const u32x4*)(qb[t] + kc * 32);
        }
        bf16x8 b[8];
        #pragma unroll
        for (int nt = 0; nt < 8; ++nt)
            b[nt] = *(const bf16x8*)(W2s + (kc * 8 + nt) * 512 + lane * 8);
        #pragma unroll
        for (int t = 0; t < 4; ++t) {
            bf16x8 a = addrelu8(p[t], q[t]);
            #pragma unroll
            for (int nt = 0; nt < 8; ++nt)
                acc[t][nt] = __builtin_amdgcn_mfma_f32_16x16x32_bf16(a, b[nt], acc[t][nt], 0, 0, 0);
        }
    }

    // ---- epilogue: +b2, relu, dot with W3, +b3; scatter to out[eid] ----
    float b2v[8], w3v[8];
    #pragma unroll
    for (int nt = 0; nt < 8; ++nt) {
        b2v[nt] = b2[nt * 16 + m];
        w3v[nt] = W3[nt * 16 + m];
    }
    float b3s = b3[0];
    #pragma unroll
    for (int t = 0; t < 4; ++t) {
        float partial[4] = {0.f, 0.f, 0.f, 0.f};
        #pragma unroll
        for (int nt = 0; nt < 8; ++nt) {
            #pragma unroll
            for (int r = 0; r < 4; ++r) {
                float x2 = acc[t][nt][r] + b2v[nt];       // C row = kq*4+r, col = nt*16+m
                x2 = x2 > 0.f ? x2 : 0.f;
                partial[r] += x2 * w3v[nt];
            }
        }
        #pragma unroll
        for (int r = 0; r < 4; ++r) {
            #pragma unroll
            for (int off = 1; off < 16; off <<= 1)
                partial[r] += __shfl_xor(partial[r], off, 64);
            int eo = __shfl(eid, t * 16 + kq * 4 + r, 64);
            if (m == 0) out[eo] = partial[r] + b3s;
        }
    }
}

extern "C" void kernel_launch(void* const* d_in, const int* in_sizes, int n_in,
                              void* d_out, int out_size, void* d_ws, size_t ws_size,
                              hipStream_t stream) {
    const float* emb = (const float*)d_in[0];
    const int*   ei  = (const int*)d_in[1];
    const float* W1  = (const float*)d_in[2];
    const float* b1  = (const float*)d_in[3];
    const float* W2  = (const float*)d_in[4];
    const float* b2  = (const float*)d_in[5];
    const float* W3  = (const float*)d_in[6];
    const float* b3  = (const float*)d_in[7];
    float* out = (float*)d_out;

    short* PQ   = (short*)((char*)d_ws + PQ_OFF);
    short* W1s  = (short*)((char*)d_ws + W1S_OFF);
    short* W2s  = (short*)((char*)d_ws + W2S_OFF);
    int*   cnt  = (int*)((char*)d_ws + CNT_OFF);
    int*   cur  = (int*)((char*)d_ws + CUR_OFF);
    int*   btot = (int*)((char*)d_ws + BTOT_OFF);
    uint2* pk   = (uint2*)((char*)d_ws + PK_OFF);

    void* args[] = {(void*)&W1, (void*)&W2, (void*)&W1s, (void*)&W2s,
                    (void*)&ei, (void*)&cnt, (void*)&btot, (void*)&cur, (void*)&pk};
    hipLaunchCooperativeKernel((const void*)prep_kernel,
                               dim3(PREP_BLOCKS), dim3(256), args, 0, stream);
    precompute_kernel<<<N_NODESC / 16, 256, 0, stream>>>(emb, W1s, b1, PQ);            // 3125 blocks
    edge_kernel<<<N_EDGES / 256, 256, 0, stream>>>(PQ, pk, W2s, b2, W3, b3, out);      // 3125 blocks
}

// Round 10
// 447.846 us; speedup vs baseline: 1.8065x; 1.8065x over previous
//
#include <hip/hip_runtime.h>
#include <hip/hip_bf16.h>
#include <stdint.h>

// Problem constants (fixed by the reference)
#define N_EDGES   800000
#define N_NODESC  50000
#define HID       128
#define CSTRIDE   8          // cnt/cursor stride in ints (32 B): kills same-line atomic serialization

typedef __attribute__((ext_vector_type(8))) short bf16x8;  // 8 bf16 = 4 VGPRs (MFMA A/B frag)
typedef __attribute__((ext_vector_type(4))) float f32x4;   // MFMA C/D frag
typedef __attribute__((ext_vector_type(4))) unsigned int u32x4;

__device__ __forceinline__ short f2bf(float f) {
    union { float f; uint32_t u; } v; v.f = f;
    uint32_t r = v.u + 0x7FFFu + ((v.u >> 16) & 1u);   // round-to-nearest-even
    return (short)(r >> 16);
}

// pack two f32 -> bf16x2 (RNE) via native v_cvt_pk_bf16_f32 on gfx950
__device__ __forceinline__ uint32_t packbf2(float lo, float hi) {
    float2 t; t.x = lo; t.y = hi;
    __hip_bfloat162 h = __float22bfloat162_rn(t);
    uint32_t u;
    __builtin_memcpy(&u, &h, 4);       // __hip_bfloat162 not trivially copyable -> memcpy pun
    return u;
}

// packed bf16x2 (a+b) then relu: native v_pk_add_bf16 (one RNE rounding) + sign-mask relu
__device__ __forceinline__ uint32_t addrelu2(uint32_t a, uint32_t b) {
    __hip_bfloat162 ha, hb;
    __builtin_memcpy(&ha, &a, 4);
    __builtin_memcpy(&hb, &b, 4);
    __hip_bfloat162 s = __hadd2(ha, hb);
    uint32_t x;
    __builtin_memcpy(&x, &s, 4);
    uint32_t neg = (x & 0x80008000u) >> 15;      // 1 at bit0/bit16 where half negative
    return x & ~(neg * 0xFFFFu);                 // zero negative halves
}
__device__ __forceinline__ bf16x8 addrelu8(u32x4 p, u32x4 q) {
    u32x4 r;
    #pragma unroll
    for (int j = 0; j < 4; ++j) r[j] = addrelu2(p[j], q[j]);
    bf16x8 out;
    __builtin_memcpy(&out, &r, 16);
    return out;
}

// ---------------- workspace layout ----------------
#define PQ_OFF    0UL                          // bf16 [50000][1024]
#define W1S_OFF   102400000UL                  // 50000*1024*2
#define W2S_OFF   (W1S_OFF + 262144UL)
#define CNTS_OFF  (W2S_OFF + 131072UL)         // int[50000*CSTRIDE]  (strided histogram)
#define CURS_OFF  (CNTS_OFF + 1600000UL)       // int[50000*CSTRIDE]  (strided cursors)
#define BSUM_OFF  (CURS_OFF + 1600000UL)       // int[196] block sums
#define BSCAN_OFF (BSUM_OFF + 1024UL)          // int[196] exclusive block offsets
#define PK_OFF    (BSCAN_OFF + 1024UL)         // uint2[800000] col-sorted packed edges
// total ws needed: PK_OFF + 6,400,000 = 112,395,264 bytes

// ============ kernel 0: swizzle + zero strided histogram (independent tasks, one node) ============
__global__ __launch_bounds__(256) void init_kernel(const float* __restrict__ W1,
                                                   const float* __restrict__ W2,
                                                   short* __restrict__ W1s,
                                                   short* __restrict__ W2s,
                                                   int* __restrict__ cntS) {
    int b = blockIdx.x;
    int tid = threadIdx.x;
    if (b < 96) {
        int t = b * 256 + tid;
        int lane = t & 63;
        int kq = lane >> 4;
        int nn = lane & 15;
        if (t < 16384) {          // W1cat: K=128, N=1024 -> kc 0..3, nt 0..63
            int frag = t >> 6;
            int kc = frag >> 6;
            int nt = frag & 63;
            int n = nt * 16 + nn;
            int kbase = kc * 32 + kq * 8;
            bf16x8 v;
            #pragma unroll
            for (int j = 0; j < 8; ++j) {
                int k = kbase + j;
                float f = (n < 512) ? W1[k * 512 + n] : W1[(128 + k) * 512 + (n - 512)];
                v[j] = f2bf(f);
            }
            *(bf16x8*)(W1s + frag * 512 + lane * 8) = v;
        } else if (t < 24576) {   // W2: K=512, N=128 -> kc 0..15, nt 0..7
            int t2 = t - 16384;
            int frag = t2 >> 6;
            int kc = frag >> 3;
            int nt = frag & 7;
            int n = nt * 16 + nn;
            int kbase = kc * 32 + kq * 8;
            bf16x8 v;
            #pragma unroll
            for (int j = 0; j < 8; ++j) v[j] = f2bf(W2[(kbase + j) * HID + n]);
            *(bf16x8*)(W2s + frag * 512 + lane * 8) = v;
        }
    } else {
        int i = (b - 96) * 256 + tid;
        if (i < N_NODESC) cntS[i * CSTRIDE] = 0;
    }
}

// ============ counting sort by col, strided counters ============
__global__ __launch_bounds__(256) void hist_kernel(const int* __restrict__ ei,
                                                   int* __restrict__ cntS) {
    int e = blockIdx.x * 256 + threadIdx.x;
    atomicAdd(&cntS[ei[e] * CSTRIDE], 1);
}

// scanA: 196 blocks, each sums 256 buckets -> bsum[b]
__global__ __launch_bounds__(256) void scanA_kernel(const int* __restrict__ cntS,
                                                    int* __restrict__ bsum) {
    __shared__ int wsum[4];
    int tid = threadIdx.x;
    int i = blockIdx.x * 256 + tid;
    int v = (i < N_NODESC) ? cntS[i * CSTRIDE] : 0;
    #pragma unroll
    for (int off = 32; off; off >>= 1) v += __shfl_down(v, off, 64);
    if ((tid & 63) == 0) wsum[tid >> 6] = v;
    __syncthreads();
    if (tid == 0) bsum[blockIdx.x] = wsum[0] + wsum[1] + wsum[2] + wsum[3];
}

// scanB: 1 block, exclusive scan of 196 block sums
__global__ __launch_bounds__(256) void scanB_kernel(const int* __restrict__ bsum,
                                                    int* __restrict__ bscan) {
    __shared__ int woff[4];
    int tid = threadIdx.x;
    int lane = tid & 63, wv = tid >> 6;
    int v = (tid < 196) ? bsum[tid] : 0;
    int run = v;
    #pragma unroll
    for (int off = 1; off < 64; off <<= 1) {
        int t = __shfl_up(run, off, 64);
        if (lane >= off) run += t;
    }
    if (lane == 63) woff[wv] = run;
    __syncthreads();
    if (tid == 0) {
        int acc = 0;
        #pragma unroll
        for (int i = 0; i < 4; ++i) { int t = woff[i]; woff[i] = acc; acc += t; }
    }
    __syncthreads();
    if (tid < 196) bscan[tid] = woff[wv] + run - v;   // exclusive
}

// scanC: 196 blocks, in-block exclusive scan + block offset -> strided cursor
__global__ __launch_bounds__(256) void scanC_kernel(const int* __restrict__ cntS,
                                                    const int* __restrict__ bscan,
                                                    int* __restrict__ curS) {
    __shared__ int woff[4];
    int tid = threadIdx.x;
    int lane = tid & 63, wv = tid >> 6;
    int i = blockIdx.x * 256 + tid;
    int v = (i < N_NODESC) ? cntS[i * CSTRIDE] : 0;
    int run = v;
    #pragma unroll
    for (int off = 1; off < 64; off <<= 1) {
        int t = __shfl_up(run, off, 64);
        if (lane >= off) run += t;
    }
    if (lane == 63) woff[wv] = run;
    __syncthreads();
    if (tid == 0) {
        int acc = 0;
        #pragma unroll
        for (int j = 0; j < 4; ++j) { int t = woff[j]; woff[j] = acc; acc += t; }
    }
    __syncthreads();
    if (i < N_NODESC) curS[i * CSTRIDE] = bscan[blockIdx.x] + woff[wv] + run - v;
}

__global__ __launch_bounds__(256) void scatter_kernel(const int* __restrict__ ei,
                                                      int* __restrict__ curS,
                                                      uint2* __restrict__ pk) {
    int e = blockIdx.x * 256 + threadIdx.x;
    int c = ei[e];
    int r = ei[N_EDGES + e];
    int slot = atomicAdd(&curS[c * CSTRIDE], 1);
    uint2 v;
    v.x = ((uint32_t)c << 16) | (uint32_t)r;
    v.y = (uint32_t)e;
    pk[slot] = v;
}

// ============ kernel 1: PQ = emb @ W1cat (+b1 on P half) — exact R6 version ============
__global__ __launch_bounds__(256) void precompute_kernel(const float* __restrict__ emb,
                                                         const short* __restrict__ W1s,
                                                         const float* __restrict__ b1,
                                                         short* __restrict__ PQ) {
    __shared__ short tile[4][16][272];   // 16 rows x 256 cols, stride 272 shorts (544 B)
    int lane = threadIdx.x & 63;
    int w = threadIdx.x >> 6;
    int nb = blockIdx.x * 16;
    int m = lane & 15;
    int kq = lane >> 4;

    const float* arow = emb + (size_t)(nb + m) * 128 + kq * 8;

    f32x4 acc[16];
    #pragma unroll
    for (int i = 0; i < 16; ++i) acc[i] = (f32x4){0.f, 0.f, 0.f, 0.f};

    #pragma unroll
    for (int kc = 0; kc < 4; ++kc) {
        f32x4 x0 = *(const f32x4*)(arow + kc * 32);
        f32x4 x1 = *(const f32x4*)(arow + kc * 32 + 4);
        u32x4 au;
        au[0] = packbf2(x0[0], x0[1]); au[1] = packbf2(x0[2], x0[3]);
        au[2] = packbf2(x1[0], x1[1]); au[3] = packbf2(x1[2], x1[3]);
        bf16x8 a;
        __builtin_memcpy(&a, &au, 16);
        #pragma unroll
        for (int nt = 0; nt < 16; ++nt) {
            int frag = kc * 64 + (w * 16 + nt);
            bf16x8 bb = *(const bf16x8*)(W1s + frag * 512 + lane * 8);
            acc[nt] = __builtin_amdgcn_mfma_f32_16x16x32_bf16(a, bb, acc[nt], 0, 0, 0);
        }
    }

    // C/D layout: col = lane&15, row = (lane>>4)*4 + r.  Fold b1 into the P half (n<512).
    #pragma unroll
    for (int nt = 0; nt < 16; ++nt) {
        int n = w * 256 + nt * 16 + m;
        float bias = (n < 512) ? b1[n] : 0.0f;
        #pragma unroll
        for (int r = 0; r < 4; ++r)
            tile[w][kq * 4 + r][nt * 16 + m] = f2bf(acc[nt][r] + bias);
    }

    #pragma unroll
    for (int s = 0; s < 8; ++s) {
        int row = s * 2 + (lane >> 5);
        int chunk = lane & 31;
        bf16x8 v = *(const bf16x8*)(&tile[w][row][chunk * 8]);
        *(bf16x8*)(PQ + (size_t)(nb + row) * 1024 + w * 256 + chunk * 8) = v;
    }
}

// ============ kernel 2: per-edge fused MLP on col-sorted edges (R7 structure, 231 us) ============
__global__ __launch_bounds__(256, 2) void edge_kernel(const short* __restrict__ PQ,
                                                      const uint2* __restrict__ pk,
                                                      const short* __restrict__ W2s,
                                                      const float* __restrict__ b2,
                                                      const float* __restrict__ W3,
                                                      const float* __restrict__ b3,
                                                      float* __restrict__ out) {
    int lane = threadIdx.x & 63;
    int w = threadIdx.x >> 6;
    int e0 = blockIdx.x * 256 + w * 64;
    int m = lane & 15;
    int kq = lane >> 4;

    uint2 pe = pk[e0 + lane];
    int idx_c = (int)(pe.x >> 16);
    int idx_r = (int)(pe.x & 0xFFFFu);
    int eid   = (int)pe.y;

    const short* pb[4];
    const short* qb[4];
    #pragma unroll
    for (int t = 0; t < 4; ++t) {
        int ce = __shfl(idx_c, t * 16 + m, 64);
        int re = __shfl(idx_r, t * 16 + m, 64);
        pb[t] = PQ + (size_t)ce * 1024 + kq * 8;          // P' half
        qb[t] = PQ + (size_t)re * 1024 + 512 + kq * 8;    // Q half
    }

    f32x4 acc[4][8];
    #pragma unroll
    for (int t = 0; t < 4; ++t)
        #pragma unroll
        for (int nt = 0; nt < 8; ++nt) acc[t][nt] = (f32x4){0.f, 0.f, 0.f, 0.f};

    #pragma unroll
    for (int kc = 0; kc < 16; ++kc) {
        u32x4 p[4], q[4];
        #pragma unroll
        for (int t = 0; t < 4; ++t) {
            p[t] = *(const u32x4*)(pb[t] + kc * 32);
            q[t] = *(const u32x4*)(qb[t] + kc * 32);
        }
        bf16x8 b[8];
        #pragma unroll
        for (int nt = 0; nt < 8; ++nt)
            b[nt] = *(const bf16x8*)(W2s + (kc * 8 + nt) * 512 + lane * 8);
        #pragma unroll
        for (int t = 0; t < 4; ++t) {
            bf16x8 a = addrelu8(p[t], q[t]);
            #pragma unroll
            for (int nt = 0; nt < 8; ++nt)
                acc[t][nt] = __builtin_amdgcn_mfma_f32_16x16x32_bf16(a, b[nt], acc[t][nt], 0, 0, 0);
        }
    }

    // ---- epilogue: +b2, relu, dot with W3, +b3; scatter to out[eid] ----
    float b2v[8], w3v[8];
    #pragma unroll
    for (int nt = 0; nt < 8; ++nt) {
        b2v[nt] = b2[nt * 16 + m];
        w3v[nt] = W3[nt * 16 + m];
    }
    float b3s = b3[0];
    #pragma unroll
    for (int t = 0; t < 4; ++t) {
        float partial[4] = {0.f, 0.f, 0.f, 0.f};
        #pragma unroll
        for (int nt = 0; nt < 8; ++nt) {
            #pragma unroll
            for (int r = 0; r < 4; ++r) {
                float x2 = acc[t][nt][r] + b2v[nt];       // C row = kq*4+r, col = nt*16+m
                x2 = x2 > 0.f ? x2 : 0.f;
                partial[r] += x2 * w3v[nt];
            }
        }
        #pragma unroll
        for (int r = 0; r < 4; ++r) {
            #pragma unroll
            for (int off = 1; off < 16; off <<= 1)
                partial[r] += __shfl_xor(partial[r], off, 64);
            int eo = __shfl(eid, t * 16 + kq * 4 + r, 64);
            if (m == 0) out[eo] = partial[r] + b3s;
        }
    }
}

extern "C" void kernel_launch(void* const* d_in, const int* in_sizes, int n_in,
                              void* d_out, int out_size, void* d_ws, size_t ws_size,
                              hipStream_t stream) {
    const float* emb = (const float*)d_in[0];
    const int*   ei  = (const int*)d_in[1];
    const float* W1  = (const float*)d_in[2];
    const float* b1  = (const float*)d_in[3];
    const float* W2  = (const float*)d_in[4];
    const float* b2  = (const float*)d_in[5];
    const float* W3  = (const float*)d_in[6];
    const float* b3  = (const float*)d_in[7];
    float* out = (float*)d_out;

    short* PQ    = (short*)((char*)d_ws + PQ_OFF);
    short* W1s   = (short*)((char*)d_ws + W1S_OFF);
    short* W2s   = (short*)((char*)d_ws + W2S_OFF);
    int*   cntS  = (int*)((char*)d_ws + CNTS_OFF);
    int*   curS  = (int*)((char*)d_ws + CURS_OFF);
    int*   bsum  = (int*)((char*)d_ws + BSUM_OFF);
    int*   bscan = (int*)((char*)d_ws + BSCAN_OFF);
    uint2* pk    = (uint2*)((char*)d_ws + PK_OFF);

    init_kernel<<<96 + 196, 256, 0, stream>>>(W1, W2, W1s, W2s, cntS);
    hist_kernel<<<N_EDGES / 256, 256, 0, stream>>>(ei, cntS);
    scanA_kernel<<<196, 256, 0, stream>>>(cntS, bsum);
    scanB_kernel<<<1, 256, 0, stream>>>(bsum, bscan);
    scanC_kernel<<<196, 256, 0, stream>>>(cntS, bscan, curS);
    scatter_kernel<<<N_EDGES / 256, 256, 0, stream>>>(ei, curS, pk);
    precompute_kernel<<<N_NODESC / 16, 256, 0, stream>>>(emb, W1s, b1, PQ);            // 3125 blocks
    edge_kernel<<<N_EDGES / 256, 256, 0, stream>>>(PQ, pk, W2s, b2, W3, b3, out);      // 3125 blocks
}